// Round 7
// baseline (358.616 us; speedup 1.0000x reference)
//
#include <hip/hip_runtime.h>
#include <math.h>

#define N_NODES 50000
#define N_EDGES 500000
#define NUM_RELS 16
#define GH 64          // k_mfma grid = 32*GH = 2048 blocks

typedef _Float16 f16x8 __attribute__((ext_vector_type(8)));
typedef _Float16 f16x4 __attribute__((ext_vector_type(4)));
typedef float    f32x4 __attribute__((ext_vector_type(4)));

// ---------------- ws layout (4-byte words) ----------------
// [192,208)      counts[16]
// [228,244)      cursor[16]
// [256,+N)       sn[N]
// [50256,+N)     dn[N]
// [100352,+E)    srcs[E]   (rel-sorted)
// [600352,+E)    dsts[E]
// [1100352,+E)   aes[E]
// [1600352,+1.6M) h_hi  (f16[N*64])
// [3200352,+1.6M) h_lo  (f16[N*64])
// total ~19.2 MB

__global__ void kz(int* counts, int* cursor) {
    if (threadIdx.x < NUM_RELS) { counts[threadIdx.x] = 0; cursor[threadIdx.x] = 0; }
}

// ---- node scalars sn/dn, zero out, split-f16 h, rel histogram ----
__global__ __launch_bounds__(256) void k_node(
    const float* __restrict__ h,
    const float* __restrict__ W_shared, const float* __restrict__ W_attn,
    const int* __restrict__ rel,
    float* __restrict__ sn, float* __restrict__ dn,
    float4* __restrict__ out4, int* __restrict__ counts,
    _Float16* __restrict__ h_hi, _Float16* __restrict__ h_lo) {
    __shared__ float sus[64], sud[64];
    __shared__ int hist[NUM_RELS];
    const int t = threadIdx.x, bid = blockIdx.x, nb = gridDim.x;
    if (t < 64) {
        float us = 0.f, ud = 0.f;
        for (int o = 0; o < 64; ++o) {
            float w = W_shared[o * 64 + t];
            us = fmaf(w, W_attn[o],       us);
            ud = fmaf(w, W_attn[128 + o], ud);
        }
        sus[t] = us; sud[t] = ud;
    }
    if (t < NUM_RELS) hist[t] = 0;
    __syncthreads();

    int n = bid * 256 + t;
    if (n < N_NODES) {
        const float* hp = h + (size_t)n * 64;
        float s = 0.f, d = 0.f;
#pragma unroll
        for (int i = 0; i < 64; i += 4) {
            float4 v = *(const float4*)(hp + i);
            s = fmaf(v.x, sus[i], s);     s = fmaf(v.y, sus[i + 1], s);
            s = fmaf(v.z, sus[i + 2], s); s = fmaf(v.w, sus[i + 3], s);
            d = fmaf(v.x, sud[i], d);     d = fmaf(v.y, sud[i + 1], d);
            d = fmaf(v.z, sud[i + 2], d); d = fmaf(v.w, sud[i + 3], d);
            f16x4 hi, lo;
            hi[0] = (_Float16)v.x; lo[0] = (_Float16)(v.x - (float)hi[0]);
            hi[1] = (_Float16)v.y; lo[1] = (_Float16)(v.y - (float)hi[1]);
            hi[2] = (_Float16)v.z; lo[2] = (_Float16)(v.z - (float)hi[2]);
            hi[3] = (_Float16)v.w; lo[3] = (_Float16)(v.w - (float)hi[3]);
            *(f16x4*)(h_hi + (size_t)n * 64 + i) = hi;
            *(f16x4*)(h_lo + (size_t)n * 64 + i) = lo;
        }
        sn[n] = s; dn[n] = d;
        float4 z = make_float4(0.f, 0.f, 0.f, 0.f);
#pragma unroll
        for (int i = 0; i < 16; ++i) out4[(size_t)n * 16 + i] = z;
    }
    for (int e = bid * 256 + t; e < N_EDGES; e += nb * 256)
        atomicAdd(&hist[rel[e]], 1);
    __syncthreads();
    if (t < NUM_RELS && hist[t]) atomicAdd(&counts[t], hist[t]);
}

// ---- per-edge ae + scatter SoA records into rel-sorted order ----
__global__ __launch_bounds__(256) void k_ae(
    const float4* __restrict__ he4,
    const int* __restrict__ src, const int* __restrict__ dst,
    const int* __restrict__ rel,
    const float* __restrict__ W_shared, const float* __restrict__ W_attn,
    const float* __restrict__ sn, const float* __restrict__ dn,
    const int* __restrict__ counts, int* __restrict__ cursor,
    int* __restrict__ srcs, int* __restrict__ dsts, float* __restrict__ aes) {
    __shared__ float sve[64];
    __shared__ int hist[NUM_RELS], bbase[NUM_RELS], soffs[NUM_RELS];
    const int t = threadIdx.x, bid = blockIdx.x, nb = gridDim.x;
    if (t < 64) {
        float ve = 0.f;
        for (int o = 0; o < 64; ++o)
            ve = fmaf(W_shared[o * 64 + t], W_attn[64 + o], ve);
        sve[t] = ve;
    }
    if (t == 0) {
        int acc = 0;
        for (int j = 0; j < NUM_RELS; ++j) { soffs[j] = acc; acc += counts[j]; }
    }
    for (int e0 = bid * 256; e0 < N_EDGES; e0 += nb * 256) {
        __syncthreads();
        if (t < NUM_RELS) hist[t] = 0;
        __syncthreads();
        int e = e0 + t;
        bool valid = (e < N_EDGES);
        int r = 0, lpos = 0, s_ = 0, d_ = 0; float aev = 0.f;
        if (valid) {
            s_ = src[e]; d_ = dst[e]; r = rel[e];
            const float4* hr = he4 + (size_t)e * 16;
            float acc = 0.f;
#pragma unroll
            for (int i = 0; i < 16; ++i) {
                float4 v = hr[i];
                float4 u = *(const float4*)(sve + 4 * i);
                acc += v.x * u.x + v.y * u.y + v.z * u.z + v.w * u.w;
            }
            aev = acc + sn[s_] + dn[d_];
            lpos = atomicAdd(&hist[r], 1);
        }
        __syncthreads();
        if (t < NUM_RELS) bbase[t] = hist[t] ? atomicAdd(&cursor[t], hist[t]) : 0;
        __syncthreads();
        if (valid) {
            int p = soffs[r] + bbase[r] + lpos;
            srcs[p] = s_; dsts[p] = d_; aes[p] = aev;
        }
    }
}

// ---- main: MFMA split-fp16, wave=(relation,half), 2-stage pipeline ----
__global__ __launch_bounds__(256, 4) void k_mfma(
    const _Float16* __restrict__ h_hi, const _Float16* __restrict__ h_lo,
    const float* __restrict__ W_rel,
    const int* __restrict__ counts,
    const int* __restrict__ srcs, const int* __restrict__ dsts,
    const float* __restrict__ aes, float* __restrict__ out)
{
    const int t = threadIdx.x;
    const int lane = t & 63;
    const int quad = lane >> 4;
    const int col  = lane & 15;
    const int wib  = t >> 6;
    const int rh   = blockIdx.x & 31;
    const int r    = rh & 15;
    const int half = rh >> 4;
    const int g    = blockIdx.x >> 5;
    const int wr   = g * 4 + wib;
    const int WPR  = GH * 4;
    const int STEP = WPR * 16;

    int begin = 0, cr = 0;
#pragma unroll
    for (int j = 0; j < NUM_RELS; ++j) {
        int c = counts[j];
        if (j < r) begin += c;
        if (j == r) cr = c;
    }
    begin = __builtin_amdgcn_readfirstlane(begin);
    const int end = __builtin_amdgcn_readfirstlane(begin + cr);

    // B fragments for this (r, half): 2 kb-blocks x 2 n-tiles, hi/lo split
    const float* Wb = W_rel + (size_t)r * 4096;
    f16x8 bh[2][2], bl[2][2];
#pragma unroll
    for (int kb = 0; kb < 2; ++kb)
#pragma unroll
        for (int n2 = 0; n2 < 2; ++n2)
#pragma unroll
            for (int j = 0; j < 8; ++j) {
                float w = Wb[(kb * 32 + quad * 8 + j) * 64 + (half * 2 + n2) * 16 + col];
                _Float16 hi = (_Float16)w;
                bh[kb][n2][j] = hi;
                bl[kb][n2][j] = (_Float16)(w - (float)hi);
            }

    int base = begin + wr * 16;
    if (base >= end) return;

    // --- pipeline stage 0 prime ---
    int sv0, dv0; float av0;
    {
        int m16 = end - base; if (m16 > 16) m16 = 16;
        int ridx = base + (col < m16 ? col : m16 - 1);
        sv0 = srcs[ridx]; dv0 = dsts[ridx];
        av0 = (col < m16) ? aes[ridx] : 0.f;
    }
    f16x8 ah0, ah1, al0, al1;
    {
        const _Float16* ph = h_hi + (size_t)sv0 * 64 + quad * 8;
        const _Float16* pl = h_lo + (size_t)sv0 * 64 + quad * 8;
        ah0 = *(const f16x8*)ph;        ah1 = *(const f16x8*)(ph + 32);
        al0 = *(const f16x8*)pl;        al1 = *(const f16x8*)(pl + 32);
    }

    for (; base < end; base += STEP) {
        const int nb = base + STEP;
        // prefetch next batch (records then A-fragments)
        int sv1 = 0, dv1 = 0; float av1 = 0.f;
        f16x8 nah0, nah1, nal0, nal1;
        if (nb < end) {
            int m16 = end - nb; if (m16 > 16) m16 = 16;
            int ridx = nb + (col < m16 ? col : m16 - 1);
            sv1 = srcs[ridx]; dv1 = dsts[ridx];
            av1 = (col < m16) ? aes[ridx] : 0.f;
            const _Float16* ph = h_hi + (size_t)sv1 * 64 + quad * 8;
            const _Float16* pl = h_lo + (size_t)sv1 * 64 + quad * 8;
            nah0 = *(const f16x8*)ph;   nah1 = *(const f16x8*)(ph + 32);
            nal0 = *(const f16x8*)pl;   nal1 = *(const f16x8*)(pl + 32);
        }

        // compute current batch
        f32x4 acc0 = {0.f, 0.f, 0.f, 0.f};
        f32x4 acc1 = {0.f, 0.f, 0.f, 0.f};
        acc0 = __builtin_amdgcn_mfma_f32_16x16x32_f16(ah0, bh[0][0], acc0, 0, 0, 0);
        acc1 = __builtin_amdgcn_mfma_f32_16x16x32_f16(ah0, bh[0][1], acc1, 0, 0, 0);
        acc0 = __builtin_amdgcn_mfma_f32_16x16x32_f16(ah0, bl[0][0], acc0, 0, 0, 0);
        acc1 = __builtin_amdgcn_mfma_f32_16x16x32_f16(ah0, bl[0][1], acc1, 0, 0, 0);
        acc0 = __builtin_amdgcn_mfma_f32_16x16x32_f16(al0, bh[0][0], acc0, 0, 0, 0);
        acc1 = __builtin_amdgcn_mfma_f32_16x16x32_f16(al0, bh[0][1], acc1, 0, 0, 0);
        acc0 = __builtin_amdgcn_mfma_f32_16x16x32_f16(ah1, bh[1][0], acc0, 0, 0, 0);
        acc1 = __builtin_amdgcn_mfma_f32_16x16x32_f16(ah1, bh[1][1], acc1, 0, 0, 0);
        acc0 = __builtin_amdgcn_mfma_f32_16x16x32_f16(ah1, bl[1][0], acc0, 0, 0, 0);
        acc1 = __builtin_amdgcn_mfma_f32_16x16x32_f16(ah1, bl[1][1], acc1, 0, 0, 0);
        acc0 = __builtin_amdgcn_mfma_f32_16x16x32_f16(al1, bh[1][0], acc0, 0, 0, 0);
        acc1 = __builtin_amdgcn_mfma_f32_16x16x32_f16(al1, bh[1][1], acc1, 0, 0, 0);

        // epilogue: row m = quad*4+reg lives in lane m (<16) for dv/av
#pragma unroll
        for (int reg = 0; reg < 4; ++reg) {
            const int m = quad * 4 + reg;
            const int   dm = __shfl(dv0, m, 64);
            const float am = __shfl(av0, m, 64);
            float* op = out + (size_t)dm * 64 + half * 32 + col;
            unsafeAtomicAdd(op,      am * acc0[reg]);
            unsafeAtomicAdd(op + 16, am * acc1[reg]);
        }

        // rotate pipeline
        sv0 = sv1; dv0 = dv1; av0 = av1;
        ah0 = nah0; ah1 = nah1; al0 = nal0; al1 = nal1;
    }
}

// ---- relu ----
__global__ __launch_bounds__(256) void k_relu(float4* __restrict__ out4) {
    for (int i = blockIdx.x * 256 + threadIdx.x; i < N_NODES * 16; i += gridDim.x * 256) {
        float4 v = out4[i];
        v.x = fmaxf(v.x, 0.f); v.y = fmaxf(v.y, 0.f);
        v.z = fmaxf(v.z, 0.f); v.w = fmaxf(v.w, 0.f);
        out4[i] = v;
    }
}

extern "C" void kernel_launch(void* const* d_in, const int* in_sizes, int n_in,
                              void* d_out, int out_size, void* d_ws, size_t ws_size,
                              hipStream_t stream) {
    const float*  h        = (const float*)d_in[0];
    const float4* he4      = (const float4*)d_in[1];
    const int*    src      = (const int*)d_in[2];
    const int*    dst      = (const int*)d_in[3];
    const int*    rel      = (const int*)d_in[4];
    const float*  W_shared = (const float*)d_in[5];
    const float*  W_attn   = (const float*)d_in[6];
    const float*  W_rel    = (const float*)d_in[7];
    float*        out      = (float*)d_out;

    int*      counts = (int*)d_ws + 192;
    int*      cursor = (int*)d_ws + 228;
    float*    sn     = (float*)d_ws + 256;
    float*    dn     = (float*)d_ws + 50256;
    int*      srcs   = (int*)d_ws + 100352;
    int*      dsts   = (int*)d_ws + 600352;
    float*    aes    = (float*)d_ws + 1100352;
    _Float16* h_hi   = (_Float16*)((int*)d_ws + 1600352);
    _Float16* h_lo   = (_Float16*)((int*)d_ws + 3200352);

    kz<<<1, 64, 0, stream>>>(counts, cursor);
    k_node<<<(N_NODES + 255) / 256, 256, 0, stream>>>(h, W_shared, W_attn, rel,
                                                      sn, dn, (float4*)out, counts,
                                                      h_hi, h_lo);
    k_ae<<<2048, 256, 0, stream>>>(he4, src, dst, rel, W_shared, W_attn,
                                   sn, dn, counts, cursor, srcs, dsts, aes);
    k_mfma<<<32 * GH, 256, 0, stream>>>(h_hi, h_lo, W_rel, counts, srcs, dsts, aes, out);
    k_relu<<<1024, 256, 0, stream>>>((float4*)out);
}